// Round 1
// baseline (355.664 us; speedup 1.0000x reference)
//
#include <hip/hip_runtime.h>
#include <math.h>

#define N_NODES 50000
#define F_IN 128
#define F_HID 128
#define F_OUT 64

// ---------------------------------------------------------------------------
// Detect whether edge_index arrived as int32 (stride 1) or int64 (stride 2,
// little-endian low word holds the value since all indices < 2^31).
// If int64, every odd 32-bit word is 0; for random int32 data that is
// impossible across 32 samples.
// ---------------------------------------------------------------------------
__global__ void detect_idx(const int* __restrict__ idx, int* __restrict__ flag) {
    if (blockIdx.x == 0 && threadIdx.x == 0) {
        int nz = 0;
#pragma unroll
        for (int i = 0; i < 32; ++i) nz += (idx[2 * i + 1] != 0) ? 1 : 0;
        flag[0] = (nz == 0) ? 2 : 1;  // element stride in 32-bit words
    }
}

__global__ void count_edges(const int* __restrict__ idx, const int* __restrict__ flag,
                            int E, int* __restrict__ cnt) {
    int st = flag[0];
    int e = blockIdx.x * blockDim.x + threadIdx.x;
    if (e < E) {
        int d = idx[(size_t)(E + e) * st];
        atomicAdd(&cnt[d], 1);
    }
}

__global__ void compute_dinv(const int* __restrict__ cnt, float* __restrict__ dinv) {
    int i = blockIdx.x * blockDim.x + threadIdx.x;
    if (i < N_NODES) dinv[i] = rsqrtf((float)(cnt[i] + 1));  // +1 self-loop, deg>=1
}

// Single-block exclusive prefix sum over cnt[0..n) -> offs, cursor (copy).
// 1024 threads, 4 elements/thread/chunk, wave shuffle scan (no Hillis-Steele
// sync storm). ~13 chunks for n=50000.
__global__ __launch_bounds__(1024) void scan_offsets(const int* __restrict__ cnt,
                                                     int* __restrict__ offs,
                                                     int* __restrict__ cursor, int n) {
    __shared__ int wsum[16];
    __shared__ int carry_s;
    int tid = threadIdx.x;
    int lane = tid & 63;
    int wid = tid >> 6;
    if (tid == 0) carry_s = 0;
    __syncthreads();
    for (int base = 0; base < n; base += 4096) {
        int i0 = base + tid * 4;
        int v0 = (i0 + 0 < n) ? cnt[i0 + 0] : 0;
        int v1 = (i0 + 1 < n) ? cnt[i0 + 1] : 0;
        int v2 = (i0 + 2 < n) ? cnt[i0 + 2] : 0;
        int v3 = (i0 + 3 < n) ? cnt[i0 + 3] : 0;
        int tot = v0 + v1 + v2 + v3;
        int sc = tot;
#pragma unroll
        for (int o = 1; o < 64; o <<= 1) {
            int t = __shfl_up(sc, o, 64);
            if (lane >= o) sc += t;
        }
        if (lane == 63) wsum[wid] = sc;
        __syncthreads();
        int carry = carry_s;
        int wpre = 0;
        for (int w = 0; w < wid; ++w) wpre += wsum[w];
        int run = carry + wpre + (sc - tot);  // exclusive prefix for this thread
        if (i0 + 0 < n) { offs[i0 + 0] = run; cursor[i0 + 0] = run; } run += v0;
        if (i0 + 1 < n) { offs[i0 + 1] = run; cursor[i0 + 1] = run; } run += v1;
        if (i0 + 2 < n) { offs[i0 + 2] = run; cursor[i0 + 2] = run; } run += v2;
        if (i0 + 3 < n) { offs[i0 + 3] = run; cursor[i0 + 3] = run; } run += v3;
        __syncthreads();
        if (tid == 0) {
            int t2 = 0;
#pragma unroll
            for (int w = 0; w < 16; ++w) t2 += wsum[w];
            carry_s = carry + t2;
        }
        __syncthreads();
    }
    if (threadIdx.x == 0) offs[n] = carry_s;
}

__global__ void scatter_edges(const int* __restrict__ idx, const int* __restrict__ flag,
                              int E, const float* __restrict__ dinv,
                              int* __restrict__ cursor, int* __restrict__ csrc,
                              float* __restrict__ cw) {
    int st = flag[0];
    int e = blockIdx.x * blockDim.x + threadIdx.x;
    if (e < E) {
        int s = idx[(size_t)e * st];
        int d = idx[(size_t)(E + e) * st];
        int p = atomicAdd(&cursor[d], 1);
        csrc[p] = s;
        cw[p] = dinv[s] * dinv[d];
    }
}

// ---------------------------------------------------------------------------
// GEMM C[M x 128] = A[M x 128] * B[128 x 128], fp32 vector ALU.
// Tile 32 rows x 128 cols per 256-thread block; thread = 4 rows x 4 cols.
// A staged transposed-free with pad-132 row stride (16B-aligned, bank-clean);
// B staged in two 64-row chunks to keep LDS < 64 KB (49 KB total).
// ---------------------------------------------------------------------------
__global__ __launch_bounds__(256) void gemm_128(const float* __restrict__ A,
                                                const float* __restrict__ B,
                                                float* __restrict__ C, int M) {
    __shared__ float As[32 * 132];
    __shared__ float Bs[64 * 128];
    int tid = threadIdx.x;
    int m0 = blockIdx.x * 32;
    int cg = tid & 31;   // col group (*4)
    int rg = tid >> 5;   // row group (*4)

#pragma unroll
    for (int it = 0; it < 4; ++it) {
        int lin = (it * 256 + tid) * 4;   // 0..4095
        int r = lin >> 7;
        int k = lin & 127;
        int row = m0 + r;
        float4 v = make_float4(0.f, 0.f, 0.f, 0.f);
        if (row < M) v = *(const float4*)&A[(size_t)row * 128 + k];
        *(float4*)&As[r * 132 + k] = v;   // (r*132+k)*4 is 16B aligned
    }

    float acc[4][4];
#pragma unroll
    for (int j = 0; j < 4; ++j)
#pragma unroll
        for (int i = 0; i < 4; ++i) acc[j][i] = 0.f;

    for (int kb = 0; kb < 2; ++kb) {
        __syncthreads();
#pragma unroll
        for (int it = 0; it < 8; ++it) {
            int lin = (it * 256 + tid) * 4;  // 0..8191
            *(float4*)&Bs[lin] = *(const float4*)&B[kb * 8192 + lin];
        }
        __syncthreads();
#pragma unroll 8
        for (int k2 = 0; k2 < 64; ++k2) {
            float4 b = *(const float4*)&Bs[k2 * 128 + cg * 4];
#pragma unroll
            for (int j = 0; j < 4; ++j) {
                float a = As[(rg * 4 + j) * 132 + kb * 64 + k2];
                acc[j][0] += a * b.x;
                acc[j][1] += a * b.y;
                acc[j][2] += a * b.z;
                acc[j][3] += a * b.w;
            }
        }
    }

#pragma unroll
    for (int j = 0; j < 4; ++j) {
        int row = m0 + rg * 4 + j;
        if (row < M) {
            float4 o = make_float4(acc[j][0], acc[j][1], acc[j][2], acc[j][3]);
            *(float4*)&C[(size_t)row * 128 + cg * 4] = o;
        }
    }
}

// C[M x 64] = A[M x 128] * B[128 x 64]. Tile 32x64, thread = 4 rows x 2 cols.
__global__ __launch_bounds__(256) void gemm_64(const float* __restrict__ A,
                                               const float* __restrict__ B,
                                               float* __restrict__ C, int M) {
    __shared__ float As[32 * 132];
    __shared__ float Bs[128 * 64];
    int tid = threadIdx.x;
    int m0 = blockIdx.x * 32;
    int cg = tid & 31;   // col group (*2)
    int rg = tid >> 5;   // row group (*4)

#pragma unroll
    for (int it = 0; it < 4; ++it) {
        int lin = (it * 256 + tid) * 4;
        int r = lin >> 7;
        int k = lin & 127;
        int row = m0 + r;
        float4 v = make_float4(0.f, 0.f, 0.f, 0.f);
        if (row < M) v = *(const float4*)&A[(size_t)row * 128 + k];
        *(float4*)&As[r * 132 + k] = v;
    }
#pragma unroll
    for (int it = 0; it < 8; ++it) {
        int lin = (it * 256 + tid) * 4;  // 0..8191
        *(float4*)&Bs[lin] = *(const float4*)&B[lin];
    }
    __syncthreads();

    float acc[4][2];
#pragma unroll
    for (int j = 0; j < 4; ++j) { acc[j][0] = 0.f; acc[j][1] = 0.f; }

#pragma unroll 8
    for (int k = 0; k < 128; ++k) {
        float2 b = *(const float2*)&Bs[k * 64 + cg * 2];
#pragma unroll
        for (int j = 0; j < 4; ++j) {
            float a = As[(rg * 4 + j) * 132 + k];
            acc[j][0] += a * b.x;
            acc[j][1] += a * b.y;
        }
    }

#pragma unroll
    for (int j = 0; j < 4; ++j) {
        int row = m0 + rg * 4 + j;
        if (row < M) {
            float2 o = make_float2(acc[j][0], acc[j][1]);
            *(float2*)&C[(size_t)row * 64 + cg * 2] = o;
        }
    }
}

// ---------------------------------------------------------------------------
// Pull-aggregation layer 1: out[g] = relu( dinv[g]^2*h[g] + sum_e w_e*h[src_e] + b1 )
// 32 lanes per node, float4 per lane -> one edge = one coalesced 512B row read.
// ---------------------------------------------------------------------------
__global__ __launch_bounds__(256) void aggregate_relu_128(
    const float* __restrict__ h, const int* __restrict__ offs,
    const int* __restrict__ csrc, const float* __restrict__ cw,
    const float* __restrict__ dinv, const float* __restrict__ bias,
    float* __restrict__ out) {
    int tid = threadIdx.x;
    int g = blockIdx.x * 8 + (tid >> 5);
    int lane = tid & 31;
    if (g >= N_NODES) return;
    const float4* hv = (const float4*)h;
    float di = dinv[g];
    float sw = di * di;
    float4 acc = hv[(size_t)g * 32 + lane];
    acc.x *= sw; acc.y *= sw; acc.z *= sw; acc.w *= sw;
    int e0 = offs[g], e1 = offs[g + 1];
    for (int e = e0; e < e1; ++e) {
        int s = csrc[e];
        float w = cw[e];
        float4 v = hv[(size_t)s * 32 + lane];
        acc.x += w * v.x; acc.y += w * v.y; acc.z += w * v.z; acc.w += w * v.w;
    }
    float4 b = ((const float4*)bias)[lane];
    acc.x = fmaxf(acc.x + b.x, 0.f);
    acc.y = fmaxf(acc.y + b.y, 0.f);
    acc.z = fmaxf(acc.z + b.z, 0.f);
    acc.w = fmaxf(acc.w + b.w, 0.f);
    ((float4*)out)[(size_t)g * 32 + lane] = acc;
}

// Pull-aggregation layer 2 + bias + 16-lane in-register softmax -> d_out.
__global__ __launch_bounds__(256) void aggregate_softmax_64(
    const float* __restrict__ h, const int* __restrict__ offs,
    const int* __restrict__ csrc, const float* __restrict__ cw,
    const float* __restrict__ dinv, const float* __restrict__ bias,
    float* __restrict__ out) {
    int tid = threadIdx.x;
    int g = blockIdx.x * 16 + (tid >> 4);
    int lane = tid & 15;
    if (g >= N_NODES) return;
    const float4* hv = (const float4*)h;
    float di = dinv[g];
    float sw = di * di;
    float4 acc = hv[(size_t)g * 16 + lane];
    acc.x *= sw; acc.y *= sw; acc.z *= sw; acc.w *= sw;
    int e0 = offs[g], e1 = offs[g + 1];
    for (int e = e0; e < e1; ++e) {
        int s = csrc[e];
        float w = cw[e];
        float4 v = hv[(size_t)s * 16 + lane];
        acc.x += w * v.x; acc.y += w * v.y; acc.z += w * v.z; acc.w += w * v.w;
    }
    float4 b = ((const float4*)bias)[lane];
    acc.x += b.x; acc.y += b.y; acc.z += b.z; acc.w += b.w;

    float m = fmaxf(fmaxf(acc.x, acc.y), fmaxf(acc.z, acc.w));
#pragma unroll
    for (int o = 1; o < 16; o <<= 1) m = fmaxf(m, __shfl_xor(m, o, 64));
    float4 e4;
    e4.x = expf(acc.x - m); e4.y = expf(acc.y - m);
    e4.z = expf(acc.z - m); e4.w = expf(acc.w - m);
    float s = e4.x + e4.y + e4.z + e4.w;
#pragma unroll
    for (int o = 1; o < 16; o <<= 1) s += __shfl_xor(s, o, 64);
    float inv = 1.0f / s;
    e4.x *= inv; e4.y *= inv; e4.z *= inv; e4.w *= inv;
    ((float4*)out)[(size_t)g * 16 + lane] = e4;
}

extern "C" void kernel_launch(void* const* d_in, const int* in_sizes, int n_in,
                              void* d_out, int out_size, void* d_ws, size_t ws_size,
                              hipStream_t stream) {
    const float* x  = (const float*)d_in[0];
    const int*   idx = (const int*)d_in[1];
    const float* W1 = (const float*)d_in[2];
    const float* b1 = (const float*)d_in[3];
    const float* W2 = (const float*)d_in[4];
    const float* b2 = (const float*)d_in[5];
    float* outp = (float*)d_out;
    int E = in_sizes[1] / 2;

    char* ws = (char*)d_ws;
    size_t off = 0;
    auto alloc = [&](size_t bytes) {
        size_t o = off;
        off += (bytes + 255) & ~(size_t)255;
        return o;
    };
    float* h1   = (float*)(ws + alloc((size_t)N_NODES * F_HID * 4));
    float* h1r  = (float*)(ws + alloc((size_t)N_NODES * F_HID * 4));
    int*   csrc = (int*)  (ws + alloc((size_t)E * 4));
    float* cw   = (float*)(ws + alloc((size_t)E * 4));
    int*   cnt  = (int*)  (ws + alloc((size_t)N_NODES * 4));
    int*   offs = (int*)  (ws + alloc((size_t)(N_NODES + 1) * 4));
    int*   cursor = (int*)(ws + alloc((size_t)N_NODES * 4));
    float* dinv = (float*)(ws + alloc((size_t)N_NODES * 4));
    int*   flag = (int*)  (ws + alloc(256));
    float* h2   = h1;  // reuse: h1 is dead once h1r exists

    hipMemsetAsync(cnt, 0, (size_t)N_NODES * 4, stream);
    detect_idx<<<1, 64, 0, stream>>>(idx, flag);
    count_edges<<<(E + 255) / 256, 256, 0, stream>>>(idx, flag, E, cnt);
    compute_dinv<<<(N_NODES + 255) / 256, 256, 0, stream>>>(cnt, dinv);
    scan_offsets<<<1, 1024, 0, stream>>>(cnt, offs, cursor, N_NODES);
    scatter_edges<<<(E + 255) / 256, 256, 0, stream>>>(idx, flag, E, dinv, cursor, csrc, cw);
    gemm_128<<<(N_NODES + 31) / 32, 256, 0, stream>>>(x, W1, h1, N_NODES);
    aggregate_relu_128<<<(N_NODES + 7) / 8, 256, 0, stream>>>(h1, offs, csrc, cw, dinv, b1, h1r);
    gemm_64<<<(N_NODES + 31) / 32, 256, 0, stream>>>(h1r, W2, h2, N_NODES);
    aggregate_softmax_64<<<(N_NODES + 15) / 16, 256, 0, stream>>>(h2, offs, csrc, cw, dinv, b2, outp);
}

// Round 2
// 322.394 us; speedup vs baseline: 1.1032x; 1.1032x over previous
//
#include <hip/hip_runtime.h>
#include <math.h>

#define N_NODES 50000
#define F_IN 128
#define F_HID 128
#define F_OUT 64

// ---------------------------------------------------------------------------
// Detect whether edge_index arrived as int32 (stride 1) or int64 (stride 2,
// low word holds value since indices < 2^31): odd words all-zero <=> int64.
// ---------------------------------------------------------------------------
__global__ void detect_idx(const int* __restrict__ idx, int* __restrict__ flag) {
    if (blockIdx.x == 0 && threadIdx.x == 0) {
        int nz = 0;
#pragma unroll
        for (int i = 0; i < 32; ++i) nz += (idx[2 * i + 1] != 0) ? 1 : 0;
        flag[0] = (nz == 0) ? 2 : 1;  // element stride in 32-bit words
    }
}

__global__ void count_edges(const int* __restrict__ idx, const int* __restrict__ flag,
                            int E, int* __restrict__ cnt) {
    int st = flag[0];
    int e = blockIdx.x * blockDim.x + threadIdx.x;
    if (e < E) {
        int d = idx[(size_t)(E + e) * st];
        atomicAdd(&cnt[d], 1);
    }
}

// ---------------------------------------------------------------------------
// Parallel exclusive scan of cnt[0..n) in 3 small kernels (replaces the
// serial single-block scan). Chunk = 4096 elements per block (1024 thr x 4).
// S1 also fuses dinv = rsqrt(deg+1).
// ---------------------------------------------------------------------------
__global__ __launch_bounds__(1024) void scan_reduce_dinv(const int* __restrict__ cnt,
                                                         float* __restrict__ dinv,
                                                         int* __restrict__ bsum, int n) {
    __shared__ int wsum[16];
    int tid = threadIdx.x, lane = tid & 63, wid = tid >> 6;
    int i0 = blockIdx.x * 4096 + tid * 4;
    int s = 0;
#pragma unroll
    for (int i = 0; i < 4; ++i) {
        if (i0 + i < n) {
            int c = cnt[i0 + i];
            s += c;
            dinv[i0 + i] = rsqrtf((float)(c + 1));
        }
    }
#pragma unroll
    for (int o = 1; o < 64; o <<= 1) s += __shfl_xor(s, o, 64);
    if (lane == 0) wsum[wid] = s;
    __syncthreads();
    if (tid == 0) {
        int t = 0;
#pragma unroll
        for (int w = 0; w < 16; ++w) t += wsum[w];
        bsum[blockIdx.x] = t;
    }
}

__global__ void scan_partials(int* __restrict__ bsum, int* __restrict__ offs,
                              int nb, int n) {
    int lane = threadIdx.x;
    int orig = (lane < nb) ? bsum[lane] : 0;
    int v = orig;
#pragma unroll
    for (int o = 1; o < 64; o <<= 1) {
        int t = __shfl_up(v, o, 64);
        if (lane >= o) v += t;
    }
    if (lane < nb) bsum[lane] = v - orig;   // exclusive
    if (lane == nb - 1) offs[n] = v;        // total
}

__global__ __launch_bounds__(1024) void scan_block(const int* __restrict__ cnt,
                                                   const int* __restrict__ bsum,
                                                   int* __restrict__ offs,
                                                   int* __restrict__ cursor, int n) {
    __shared__ int wsum[16];
    int tid = threadIdx.x, lane = tid & 63, wid = tid >> 6;
    int i0 = blockIdx.x * 4096 + tid * 4;
    int v0 = (i0 + 0 < n) ? cnt[i0 + 0] : 0;
    int v1 = (i0 + 1 < n) ? cnt[i0 + 1] : 0;
    int v2 = (i0 + 2 < n) ? cnt[i0 + 2] : 0;
    int v3 = (i0 + 3 < n) ? cnt[i0 + 3] : 0;
    int tot = v0 + v1 + v2 + v3;
    int sc = tot;
#pragma unroll
    for (int o = 1; o < 64; o <<= 1) {
        int t = __shfl_up(sc, o, 64);
        if (lane >= o) sc += t;
    }
    if (lane == 63) wsum[wid] = sc;
    __syncthreads();
    int wpre = 0;
    for (int w = 0; w < wid; ++w) wpre += wsum[w];
    int run = bsum[blockIdx.x] + wpre + (sc - tot);
    if (i0 + 0 < n) { offs[i0 + 0] = run; cursor[i0 + 0] = run; } run += v0;
    if (i0 + 1 < n) { offs[i0 + 1] = run; cursor[i0 + 1] = run; } run += v1;
    if (i0 + 2 < n) { offs[i0 + 2] = run; cursor[i0 + 2] = run; } run += v2;
    if (i0 + 3 < n) { offs[i0 + 3] = run; cursor[i0 + 3] = run; }
}

// Scatter only the source id; weights are recomputed in the aggregates from
// the L2-resident dinv table (halves scatter write traffic, kills cw array).
__global__ void scatter_edges(const int* __restrict__ idx, const int* __restrict__ flag,
                              int E, int* __restrict__ cursor, int* __restrict__ csrc) {
    int st = flag[0];
    int e = blockIdx.x * blockDim.x + threadIdx.x;
    if (e < E) {
        int s = idx[(size_t)e * st];
        int d = idx[(size_t)(E + e) * st];
        int p = atomicAdd(&cursor[d], 1);
        csrc[p] = s;
    }
}

// ---------------------------------------------------------------------------
// GEMM C[M x 128] = A[M x 128] * B[128 x 128], fp32 vector ALU.
// A staged TRANSPOSED in LDS (As[k][r], pad 36 keeps 16B alignment) so the
// inner loop is 2x ds_read_b128 per 16 FMA (was 1x b128 + 4x b32).
// ---------------------------------------------------------------------------
__global__ __launch_bounds__(256) void gemm_128(const float* __restrict__ A,
                                                const float* __restrict__ B,
                                                float* __restrict__ C, int M) {
    __shared__ float As[128 * 36];   // [k][r], 18.4 KB
    __shared__ float Bs[64 * 128];   // 32 KB
    int tid = threadIdx.x;
    int m0 = blockIdx.x * 32;
    int cg = tid & 31;   // col group (*4)
    int rg = tid >> 5;   // row group (*4)

#pragma unroll
    for (int it = 0; it < 4; ++it) {
        int lin = (it * 256 + tid) * 4;   // 0..4095
        int r = lin >> 7;
        int k = lin & 127;
        int row = m0 + r;
        float4 v = make_float4(0.f, 0.f, 0.f, 0.f);
        if (row < M) v = *(const float4*)&A[(size_t)row * 128 + k];
        As[(k + 0) * 36 + r] = v.x;
        As[(k + 1) * 36 + r] = v.y;
        As[(k + 2) * 36 + r] = v.z;
        As[(k + 3) * 36 + r] = v.w;
    }

    float acc[4][4];
#pragma unroll
    for (int j = 0; j < 4; ++j)
#pragma unroll
        for (int i = 0; i < 4; ++i) acc[j][i] = 0.f;

    for (int kb = 0; kb < 2; ++kb) {
        __syncthreads();
#pragma unroll
        for (int it = 0; it < 8; ++it) {
            int lin = (it * 256 + tid) * 4;  // 0..8191
            *(float4*)&Bs[lin] = *(const float4*)&B[kb * 8192 + lin];
        }
        __syncthreads();
#pragma unroll 4
        for (int k2 = 0; k2 < 64; ++k2) {
            int k = kb * 64 + k2;
            float4 a = *(const float4*)&As[k * 36 + rg * 4];
            float4 b = *(const float4*)&Bs[k2 * 128 + cg * 4];
            acc[0][0] += a.x * b.x; acc[0][1] += a.x * b.y; acc[0][2] += a.x * b.z; acc[0][3] += a.x * b.w;
            acc[1][0] += a.y * b.x; acc[1][1] += a.y * b.y; acc[1][2] += a.y * b.z; acc[1][3] += a.y * b.w;
            acc[2][0] += a.z * b.x; acc[2][1] += a.z * b.y; acc[2][2] += a.z * b.z; acc[2][3] += a.z * b.w;
            acc[3][0] += a.w * b.x; acc[3][1] += a.w * b.y; acc[3][2] += a.w * b.z; acc[3][3] += a.w * b.w;
        }
    }

#pragma unroll
    for (int j = 0; j < 4; ++j) {
        int row = m0 + rg * 4 + j;
        if (row < M) {
            float4 o = make_float4(acc[j][0], acc[j][1], acc[j][2], acc[j][3]);
            *(float4*)&C[(size_t)row * 128 + cg * 4] = o;
        }
    }
}

// C[M x 64] = A[M x 128] * B[128 x 64], same transposed-A scheme.
__global__ __launch_bounds__(256) void gemm_64(const float* __restrict__ A,
                                               const float* __restrict__ B,
                                               float* __restrict__ C, int M) {
    __shared__ float As[128 * 36];
    __shared__ float Bs[128 * 64];
    int tid = threadIdx.x;
    int m0 = blockIdx.x * 32;
    int cg = tid & 31;   // col group (*2)
    int rg = tid >> 5;   // row group (*4)

#pragma unroll
    for (int it = 0; it < 4; ++it) {
        int lin = (it * 256 + tid) * 4;
        int r = lin >> 7;
        int k = lin & 127;
        int row = m0 + r;
        float4 v = make_float4(0.f, 0.f, 0.f, 0.f);
        if (row < M) v = *(const float4*)&A[(size_t)row * 128 + k];
        As[(k + 0) * 36 + r] = v.x;
        As[(k + 1) * 36 + r] = v.y;
        As[(k + 2) * 36 + r] = v.z;
        As[(k + 3) * 36 + r] = v.w;
    }
#pragma unroll
    for (int it = 0; it < 8; ++it) {
        int lin = (it * 256 + tid) * 4;  // 0..8191
        *(float4*)&Bs[lin] = *(const float4*)&B[lin];
    }
    __syncthreads();

    float acc[4][2];
#pragma unroll
    for (int j = 0; j < 4; ++j) { acc[j][0] = 0.f; acc[j][1] = 0.f; }

#pragma unroll 4
    for (int k = 0; k < 128; ++k) {
        float4 a = *(const float4*)&As[k * 36 + rg * 4];
        float2 b = *(const float2*)&Bs[k * 64 + cg * 2];
        acc[0][0] += a.x * b.x; acc[0][1] += a.x * b.y;
        acc[1][0] += a.y * b.x; acc[1][1] += a.y * b.y;
        acc[2][0] += a.z * b.x; acc[2][1] += a.z * b.y;
        acc[3][0] += a.w * b.x; acc[3][1] += a.w * b.y;
    }

#pragma unroll
    for (int j = 0; j < 4; ++j) {
        int row = m0 + rg * 4 + j;
        if (row < M) {
            float2 o = make_float2(acc[j][0], acc[j][1]);
            *(float2*)&C[(size_t)row * 64 + cg * 2] = o;
        }
    }
}

// ---------------------------------------------------------------------------
// Pull-aggregation layer 1: out[g] = relu(dinv[g]^2*h[g] + sum w_e*h[src] + b1)
// 32 lanes/node, float4/lane. Edge loop unrolled x4: 4 independent 512B row
// gathers in flight per wave (MLP fix for the latency-bound profile).
// ---------------------------------------------------------------------------
__global__ __launch_bounds__(256) void aggregate_relu_128(
    const float* __restrict__ h, const int* __restrict__ offs,
    const int* __restrict__ csrc, const float* __restrict__ dinv,
    const float* __restrict__ bias, float* __restrict__ out) {
    int tid = threadIdx.x;
    int g = blockIdx.x * 8 + (tid >> 5);
    int lane = tid & 31;
    if (g >= N_NODES) return;
    const float4* hv = (const float4*)h;
    float di = dinv[g];
    float sw = di * di;
    float4 acc = hv[(size_t)g * 32 + lane];
    acc.x *= sw; acc.y *= sw; acc.z *= sw; acc.w *= sw;
    int e = offs[g], e1 = offs[g + 1];
    for (; e + 4 <= e1; e += 4) {
        int s0 = csrc[e + 0], s1 = csrc[e + 1], s2 = csrc[e + 2], s3 = csrc[e + 3];
        float4 v0 = hv[(size_t)s0 * 32 + lane];
        float4 v1 = hv[(size_t)s1 * 32 + lane];
        float4 v2 = hv[(size_t)s2 * 32 + lane];
        float4 v3 = hv[(size_t)s3 * 32 + lane];
        float w0 = dinv[s0] * di, w1 = dinv[s1] * di;
        float w2 = dinv[s2] * di, w3 = dinv[s3] * di;
        acc.x += w0 * v0.x + w1 * v1.x + w2 * v2.x + w3 * v3.x;
        acc.y += w0 * v0.y + w1 * v1.y + w2 * v2.y + w3 * v3.y;
        acc.z += w0 * v0.z + w1 * v1.z + w2 * v2.z + w3 * v3.z;
        acc.w += w0 * v0.w + w1 * v1.w + w2 * v2.w + w3 * v3.w;
    }
    for (; e < e1; ++e) {
        int s = csrc[e];
        float w = dinv[s] * di;
        float4 v = hv[(size_t)s * 32 + lane];
        acc.x += w * v.x; acc.y += w * v.y; acc.z += w * v.z; acc.w += w * v.w;
    }
    float4 b = ((const float4*)bias)[lane];
    acc.x = fmaxf(acc.x + b.x, 0.f);
    acc.y = fmaxf(acc.y + b.y, 0.f);
    acc.z = fmaxf(acc.z + b.z, 0.f);
    acc.w = fmaxf(acc.w + b.w, 0.f);
    ((float4*)out)[(size_t)g * 32 + lane] = acc;
}

// Pull-aggregation layer 2 + bias + 16-lane in-register softmax -> d_out.
__global__ __launch_bounds__(256) void aggregate_softmax_64(
    const float* __restrict__ h, const int* __restrict__ offs,
    const int* __restrict__ csrc, const float* __restrict__ dinv,
    const float* __restrict__ bias, float* __restrict__ out) {
    int tid = threadIdx.x;
    int g = blockIdx.x * 16 + (tid >> 4);
    int lane = tid & 15;
    if (g >= N_NODES) return;
    const float4* hv = (const float4*)h;
    float di = dinv[g];
    float sw = di * di;
    float4 acc = hv[(size_t)g * 16 + lane];
    acc.x *= sw; acc.y *= sw; acc.z *= sw; acc.w *= sw;
    int e = offs[g], e1 = offs[g + 1];
    for (; e + 4 <= e1; e += 4) {
        int s0 = csrc[e + 0], s1 = csrc[e + 1], s2 = csrc[e + 2], s3 = csrc[e + 3];
        float4 v0 = hv[(size_t)s0 * 16 + lane];
        float4 v1 = hv[(size_t)s1 * 16 + lane];
        float4 v2 = hv[(size_t)s2 * 16 + lane];
        float4 v3 = hv[(size_t)s3 * 16 + lane];
        float w0 = dinv[s0] * di, w1 = dinv[s1] * di;
        float w2 = dinv[s2] * di, w3 = dinv[s3] * di;
        acc.x += w0 * v0.x + w1 * v1.x + w2 * v2.x + w3 * v3.x;
        acc.y += w0 * v0.y + w1 * v1.y + w2 * v2.y + w3 * v3.y;
        acc.z += w0 * v0.z + w1 * v1.z + w2 * v2.z + w3 * v3.z;
        acc.w += w0 * v0.w + w1 * v1.w + w2 * v2.w + w3 * v3.w;
    }
    for (; e < e1; ++e) {
        int s = csrc[e];
        float w = dinv[s] * di;
        float4 v = hv[(size_t)s * 16 + lane];
        acc.x += w * v.x; acc.y += w * v.y; acc.z += w * v.z; acc.w += w * v.w;
    }
    float4 b = ((const float4*)bias)[lane];
    acc.x += b.x; acc.y += b.y; acc.z += b.z; acc.w += b.w;

    float m = fmaxf(fmaxf(acc.x, acc.y), fmaxf(acc.z, acc.w));
#pragma unroll
    for (int o = 1; o < 16; o <<= 1) m = fmaxf(m, __shfl_xor(m, o, 64));
    float4 e4;
    e4.x = expf(acc.x - m); e4.y = expf(acc.y - m);
    e4.z = expf(acc.z - m); e4.w = expf(acc.w - m);
    float s = e4.x + e4.y + e4.z + e4.w;
#pragma unroll
    for (int o = 1; o < 16; o <<= 1) s += __shfl_xor(s, o, 64);
    float inv = 1.0f / s;
    e4.x *= inv; e4.y *= inv; e4.z *= inv; e4.w *= inv;
    ((float4*)out)[(size_t)g * 16 + lane] = e4;
}

extern "C" void kernel_launch(void* const* d_in, const int* in_sizes, int n_in,
                              void* d_out, int out_size, void* d_ws, size_t ws_size,
                              hipStream_t stream) {
    const float* x  = (const float*)d_in[0];
    const int*   idx = (const int*)d_in[1];
    const float* W1 = (const float*)d_in[2];
    const float* b1 = (const float*)d_in[3];
    const float* W2 = (const float*)d_in[4];
    const float* b2 = (const float*)d_in[5];
    float* outp = (float*)d_out;
    int E = in_sizes[1] / 2;
    int nscan = (N_NODES + 4095) / 4096;  // 13

    char* ws = (char*)d_ws;
    size_t off = 0;
    auto alloc = [&](size_t bytes) {
        size_t o = off;
        off += (bytes + 255) & ~(size_t)255;
        return o;
    };
    float* h1   = (float*)(ws + alloc((size_t)N_NODES * F_HID * 4));
    float* h1r  = (float*)(ws + alloc((size_t)N_NODES * F_HID * 4));
    int*   csrc = (int*)  (ws + alloc((size_t)E * 4));
    int*   cnt  = (int*)  (ws + alloc((size_t)N_NODES * 4));
    int*   offs = (int*)  (ws + alloc((size_t)(N_NODES + 1) * 4));
    int*   cursor = (int*)(ws + alloc((size_t)N_NODES * 4));
    float* dinv = (float*)(ws + alloc((size_t)N_NODES * 4));
    int*   bsum = (int*)  (ws + alloc((size_t)nscan * 4));
    int*   flag = (int*)  (ws + alloc(256));
    float* h2   = h1;  // reuse: h1 dead once h1r exists

    hipMemsetAsync(cnt, 0, (size_t)N_NODES * 4, stream);
    detect_idx<<<1, 64, 0, stream>>>(idx, flag);
    count_edges<<<(E + 255) / 256, 256, 0, stream>>>(idx, flag, E, cnt);
    scan_reduce_dinv<<<nscan, 1024, 0, stream>>>(cnt, dinv, bsum, N_NODES);
    scan_partials<<<1, 64, 0, stream>>>(bsum, offs, nscan, N_NODES);
    scan_block<<<nscan, 1024, 0, stream>>>(cnt, bsum, offs, cursor, N_NODES);
    scatter_edges<<<(E + 255) / 256, 256, 0, stream>>>(idx, flag, E, cursor, csrc);
    gemm_128<<<(N_NODES + 31) / 32, 256, 0, stream>>>(x, W1, h1, N_NODES);
    aggregate_relu_128<<<(N_NODES + 7) / 8, 256, 0, stream>>>(h1, offs, csrc, dinv, b1, h1r);
    gemm_64<<<(N_NODES + 31) / 32, 256, 0, stream>>>(h1r, W2, h2, N_NODES);
    aggregate_softmax_64<<<(N_NODES + 15) / 16, 256, 0, stream>>>(h2, offs, csrc, dinv, b2, outp);
}